// Round 5
// baseline (222.989 us; speedup 1.0000x reference)
//
#include <hip/hip_runtime.h>
#include <hip/hip_bf16.h>
#include <stdint.h>

#define B_ 2
#define N_ 2048
#define D_ 1024
#define H_ 16
#define DK 64

typedef __bf16 bf16x8 __attribute__((ext_vector_type(8)));
typedef short s16x4 __attribute__((ext_vector_type(4)));
typedef float f32x4 __attribute__((ext_vector_type(4)));

#define EXP2SC 0.18033688011112042f  // 0.125 * log2(e)

__device__ __forceinline__ unsigned short f2bf(float f) {
    unsigned int u = __float_as_uint(f);
    u = (u + 0x7FFFu + ((u >> 16) & 1u)) >> 16;
    return (unsigned short)u;
}

__device__ __forceinline__ short2 pkbf(float a, float b) {
    __hip_bfloat162 t = __float22bfloat162_rn(float2{a, b});
    return *(short2*)&t;
}

// async global->LDS, 16B per lane; lds dest must be wave-uniform base + lane*16
__device__ __forceinline__ void glds16(const void* g, void* l) {
    __builtin_amdgcn_global_load_lds(
        (const __attribute__((address_space(1))) void*)g,
        (__attribute__((address_space(3))) void*)l, 16, 0, 0);
}

// ---------------- fused prep: convert x, transpose both weights, zero amean ----------------
// grid 5121 x 256
__global__ __launch_bounds__(256) void k_prep(const float* __restrict__ x,
                                              unsigned short* __restrict__ xb,
                                              const float* __restrict__ w_qkv,
                                              unsigned short* __restrict__ wqkvT,
                                              const float* __restrict__ w_out,
                                              unsigned short* __restrict__ woutT,
                                              float* __restrict__ amean) {
    __shared__ float tile[32][33];
    int blk = blockIdx.x, t = threadIdx.x;
    if (blk < 1024) {
        const float4* x4 = (const float4*)x;
        ushort4* o4 = (ushort4*)xb;
        int i = blk * 256 + t;
#pragma unroll
        for (int s = 0; s < 4; ++s, i += 262144) {
            float4 v = x4[i];
            ushort4 o;
            o.x = f2bf(v.x); o.y = f2bf(v.y); o.z = f2bf(v.z); o.w = f2bf(v.w);
            o4[i] = o;
        }
    } else if (blk < 4096) {
        int idx = blk - 1024;
        int c0 = (idx % 96) * 32, k0 = (idx / 96) * 32;
        int tx = t & 31, ty = t >> 5;
        for (int s = 0; s < 4; ++s)
            tile[ty + 8 * s][tx] = w_qkv[(size_t)(k0 + ty + 8 * s) * 3072 + c0 + tx];
        __syncthreads();
        for (int s = 0; s < 4; ++s)
            wqkvT[(size_t)(c0 + ty + 8 * s) * 1024 + k0 + tx] = f2bf(tile[tx][ty + 8 * s]);
    } else if (blk < 5120) {
        int idx = blk - 4096;
        int c0 = (idx % 32) * 32, k0 = (idx / 32) * 32;
        int tx = t & 31, ty = t >> 5;
        for (int s = 0; s < 4; ++s)
            tile[ty + 8 * s][tx] = w_out[(size_t)(k0 + ty + 8 * s) * 1024 + c0 + tx];
        __syncthreads();
        for (int s = 0; s < 4; ++s)
            woutT[(size_t)(c0 + ty + 8 * s) * 1024 + k0 + tx] = f2bf(tile[tx][ty + 8 * s]);
    } else {
#pragma unroll
        for (int s = 0; s < 16; ++s) amean[s * 256 + t] = 0.f;
    }
}

// ---------------- QKV GEMM: 128x128 tile; swizzled LDS; scatter q(pre-scaled),k,vT ----------
__global__ __launch_bounds__(256) void k_gemm_qkv(const unsigned short* __restrict__ A,
                                                  const unsigned short* __restrict__ BT,
                                                  const float* __restrict__ bias,
                                                  unsigned short* __restrict__ Cout,
                                                  int M, int Nn, int K) {
    __shared__ __attribute__((aligned(16))) unsigned short Alds[128 * 64];
    __shared__ __attribute__((aligned(16))) unsigned short Blds[128 * 64];
    int t = threadIdx.x;
    int lane = t & 63, w = t >> 6;
    int quad = lane >> 4, c = lane & 15;
    int wm = w >> 1, wn = w & 1;
    int bi = blockIdx.y, bj = blockIdx.x;
    const unsigned short* Abase = A + (size_t)(bi * 128) * K;
    const unsigned short* Bbase = BT + (size_t)(bj * 128) * K;

    f32x4 acc[4][4];
#pragma unroll
    for (int mf = 0; mf < 4; ++mf)
#pragma unroll
        for (int nf = 0; nf < 4; ++nf)
            acc[mf][nf] = (f32x4){0.f, 0.f, 0.f, 0.f};

    for (int k0 = 0; k0 < K; k0 += 64) {
        __syncthreads();
#pragma unroll
        for (int i = 0; i < 4; ++i) {
            int ch = i * 256 + t;  // 0..1023
            int row = ch >> 3, kc = (ch & 7) ^ (row & 7);
            glds16(&Abase[(size_t)row * K + k0 + kc * 8], (char*)Alds + ch * 16);
            glds16(&Bbase[(size_t)row * K + k0 + kc * 8], (char*)Blds + ch * 16);
        }
        __syncthreads();
#pragma unroll
        for (int ks = 0; ks < 2; ++ks) {
            bf16x8 af[4], bfr[4];
#pragma unroll
            for (int mf = 0; mf < 4; ++mf)
                af[mf] = *(const bf16x8*)&Alds[(wm * 64 + mf * 16 + c) * 64 +
                                               (((ks * 4 + quad) ^ (c & 7)) * 8)];
#pragma unroll
            for (int nf = 0; nf < 4; ++nf)
                bfr[nf] = *(const bf16x8*)&Blds[(wn * 64 + nf * 16 + c) * 64 +
                                                (((ks * 4 + quad) ^ (c & 7)) * 8)];
#pragma unroll
            for (int mf = 0; mf < 4; ++mf)
#pragma unroll
                for (int nf = 0; nf < 4; ++nf)
                    acc[mf][nf] = __builtin_amdgcn_mfma_f32_16x16x32_bf16(af[mf], bfr[nf],
                                                                          acc[mf][nf], 0, 0, 0);
        }
    }

#pragma unroll
    for (int mf = 0; mf < 4; ++mf)
#pragma unroll
        for (int nf = 0; nf < 4; ++nf) {
            int j = bj * 128 + wn * 64 + nf * 16 + c;
            float bv = bias[j];
            int h = j / 192, r2 = j % 192;
            int which = r2 >> 6, d = r2 & 63;
#pragma unroll
            for (int r = 0; r < 4; ++r) {
                int i = bi * 128 + wm * 64 + mf * 16 + quad * 4 + r;
                float v = acc[mf][nf][r] + bv;
                if (which == 0) v *= EXP2SC;  // fold softmax scale + log2e into Q
                int b = i >> 11, n = i & 2047;
                size_t dst;
                if (which < 2)
                    dst = (size_t)which * 4194304 + (((size_t)(h * 2 + b) * 2048 + n) * 64 + d);
                else
                    dst = (size_t)2 * 4194304 + (((size_t)(h * 2 + b) * 64 + d) * 2048 + n);
                Cout[dst] = f2bf(v);
            }
        }
}

// ---------------- out-proj GEMM: 64x128 tile, swizzled LDS, fp32 out ----------------
__global__ __launch_bounds__(256) void k_gemm_out(const unsigned short* __restrict__ A,
                                                  const unsigned short* __restrict__ BT,
                                                  const float* __restrict__ bias,
                                                  float* __restrict__ C,
                                                  int M, int Nn, int K) {
    __shared__ __attribute__((aligned(16))) unsigned short Alds[64 * 64];
    __shared__ __attribute__((aligned(16))) unsigned short Blds[128 * 64];
    int t = threadIdx.x;
    int lane = t & 63, w = t >> 6;
    int quad = lane >> 4, c = lane & 15;
    int wm = w >> 1, wn = w & 1;
    int bi = blockIdx.y, bj = blockIdx.x;
    const unsigned short* Abase = A + (size_t)(bi * 64) * K;
    const unsigned short* Bbase = BT + (size_t)(bj * 128) * K;

    f32x4 acc[2][4];
#pragma unroll
    for (int mf = 0; mf < 2; ++mf)
#pragma unroll
        for (int nf = 0; nf < 4; ++nf)
            acc[mf][nf] = (f32x4){0.f, 0.f, 0.f, 0.f};

    for (int k0 = 0; k0 < K; k0 += 64) {
        __syncthreads();
#pragma unroll
        for (int i = 0; i < 2; ++i) {
            int ch = i * 256 + t;
            int row = ch >> 3, kc = (ch & 7) ^ (row & 7);
            glds16(&Abase[(size_t)row * K + k0 + kc * 8], (char*)Alds + ch * 16);
        }
#pragma unroll
        for (int i = 0; i < 4; ++i) {
            int ch = i * 256 + t;
            int row = ch >> 3, kc = (ch & 7) ^ (row & 7);
            glds16(&Bbase[(size_t)row * K + k0 + kc * 8], (char*)Blds + ch * 16);
        }
        __syncthreads();
#pragma unroll
        for (int ks = 0; ks < 2; ++ks) {
            bf16x8 af[2], bfr[4];
#pragma unroll
            for (int mf = 0; mf < 2; ++mf)
                af[mf] = *(const bf16x8*)&Alds[(wm * 32 + mf * 16 + c) * 64 +
                                               (((ks * 4 + quad) ^ (c & 7)) * 8)];
#pragma unroll
            for (int nf = 0; nf < 4; ++nf)
                bfr[nf] = *(const bf16x8*)&Blds[(wn * 64 + nf * 16 + c) * 64 +
                                                (((ks * 4 + quad) ^ (c & 7)) * 8)];
#pragma unroll
            for (int mf = 0; mf < 2; ++mf)
#pragma unroll
                for (int nf = 0; nf < 4; ++nf)
                    acc[mf][nf] = __builtin_amdgcn_mfma_f32_16x16x32_bf16(af[mf], bfr[nf],
                                                                          acc[mf][nf], 0, 0, 0);
        }
    }

#pragma unroll
    for (int mf = 0; mf < 2; ++mf)
#pragma unroll
        for (int nf = 0; nf < 4; ++nf) {
            int j = bj * 128 + wn * 64 + nf * 16 + c;
            float bv = bias[j];
#pragma unroll
            for (int r = 0; r < 4; ++r) {
                int i = bi * 64 + wm * 32 + mf * 16 + quad * 4 + r;
                C[(size_t)i * Nn + j] = acc[mf][nf][r] + bv;
            }
        }
}

// ---------------- attention: ping-pong staging, XCD-swizzled 1-D grid (512 blocks) ---------
// 512 threads, 8 waves x 16 q-rows. hb = bi&31 (clusters per XCD), qt = bi>>5.
__global__ __launch_bounds__(512) void k_attn(const unsigned short* __restrict__ Q,
                                              const unsigned short* __restrict__ Kc,
                                              const unsigned short* __restrict__ VT,
                                              unsigned short* __restrict__ ctx,
                                              float* __restrict__ lrs_out) {
    __shared__ __attribute__((aligned(16))) unsigned short lds[16384];  // 2 x (K 8KB + V 8KB)
    int t = threadIdx.x, lane = t & 63, w = t >> 6;
    int quad = lane >> 4, c = lane & 15;
    int bi = blockIdx.x;
    int hb = bi & 31, qt = bi >> 5;
    int h = hb >> 1, b = hb & 1;
    const unsigned short* qbase = Q + (size_t)hb * 131072 + (size_t)(qt * 128 + w * 16) * 64;
    const unsigned short* kbase = Kc + (size_t)hb * 131072;
    const unsigned short* vtbase = VT + (size_t)hb * 131072;

    int srow = t >> 3, sB = t & 7;
    int sgoff = srow * 64 + ((sB ^ (srow & 7)) * 8);
    int vgoff = srow * 2048 + ((sB ^ (srow & 7)) * 8);

    // Q fragments (pre-scaled by EXP2SC in the QKV epilogue)
    bf16x8 qf[2];
#pragma unroll
    for (int ks = 0; ks < 2; ++ks)
        qf[ks] = *(const bf16x8*)&qbase[c * 64 + ks * 32 + quad * 8];

    // prologue: stage chunk 0 into buffer 0
    glds16(&kbase[sgoff], (char*)lds + t * 16);
    glds16(&vtbase[vgoff], (char*)(lds + 4096) + t * 16);

    f32x4 acc[4];
#pragma unroll
    for (int ds = 0; ds < 4; ++ds) acc[ds] = (f32x4){0.f, 0.f, 0.f, 0.f};
    float lsum = 0.f;

    for (int kb = 0; kb < 32; ++kb) {
        const unsigned short* Kb = lds + (kb & 1) * 8192;
        const unsigned short* Vb = Kb + 4096;
        __syncthreads();  // buffer kb staged (drains own glds from prev iter)
        if (kb < 31) {    // prefetch next chunk into the other buffer
            unsigned short* Kn = lds + ((kb + 1) & 1) * 8192;
            glds16(&kbase[(size_t)(kb + 1) * 4096 + sgoff], (char*)Kn + t * 16);
            glds16(&vtbase[(size_t)(kb + 1) * 64 + vgoff], (char*)(Kn + 4096) + t * 16);
        }

        // S^T tiles: row=key=quad*4+r, col=q=c
        f32x4 st[4];
#pragma unroll
        for (int ksub = 0; ksub < 4; ++ksub) st[ksub] = (f32x4){0.f, 0.f, 0.f, 0.f};
#pragma unroll
        for (int ks = 0; ks < 2; ++ks)
#pragma unroll
            for (int ksub = 0; ksub < 4; ++ksub) {
                bf16x8 kf = *(const bf16x8*)&Kb[(ksub * 16 + c) * 64 +
                                                (((ks * 4 + quad) ^ (c & 7)) * 8)];
                st[ksub] = __builtin_amdgcn_mfma_f32_16x16x32_bf16(kf, qf[ks], st[ksub], 0, 0, 0);
            }
        // exp2 in-register -> PV A-frags -> PV
#pragma unroll
        for (int ksub = 0; ksub < 4; ++ksub) {
            float p0 = __builtin_amdgcn_exp2f(st[ksub][0]);
            float p1 = __builtin_amdgcn_exp2f(st[ksub][1]);
            float p2 = __builtin_amdgcn_exp2f(st[ksub][2]);
            float p3 = __builtin_amdgcn_exp2f(st[ksub][3]);
            lsum += (p0 + p1) + (p2 + p3);
            short2 lo = pkbf(p0, p1), hi = pkbf(p2, p3);
            s16x4 pf = (s16x4){lo.x, lo.y, hi.x, hi.y};
            s16x4 vf[4];
#pragma unroll
            for (int ds = 0; ds < 4; ++ds) {
                int row = ds * 16 + c;
                vf[ds] = *(const s16x4*)&Vb[row * 64 +
                                            (((2 * ksub + (quad >> 1)) ^ (row & 7)) * 8) +
                                            (quad & 1) * 4];
            }
#pragma unroll
            for (int ds = 0; ds < 4; ++ds)
                acc[ds] = __builtin_amdgcn_mfma_f32_16x16x16bf16_1k(pf, vf[ds], acc[ds], 0, 0, 0);
        }
    }

    // l: reduce over quads (q lives on c)
    float v = lsum;
    v += __shfl_xor(v, 16);
    v += __shfl_xor(v, 32);
    if (lane < 16)
        lrs_out[hb * 2048 + qt * 128 + w * 16 + c] =
            -(__builtin_amdgcn_logf(v) + 15.0f);  // log2(1/(l*H*N))
    float linv = 1.0f / v;
    float ir[4];
#pragma unroll
    for (int r = 0; r < 4; ++r) ir[r] = __shfl(linv, quad * 4 + r);
#pragma unroll
    for (int ds = 0; ds < 4; ++ds)
#pragma unroll
        for (int r = 0; r < 4; ++r) {
            int n = qt * 128 + w * 16 + quad * 4 + r;
            ctx[((size_t)(b * 2048 + n)) * 1024 + h * 64 + ds * 16 + c] =
                f2bf(acc[ds][r] * ir[r]);
        }
}

// ---------------- attn_mean: ping-pong Q staging, XCD-swizzled 1-D grid ----------------
// 512 threads, 8 waves x 16 keys. hb = bi&31, kt = bi>>5.
__global__ __launch_bounds__(512) void k_amean(const unsigned short* __restrict__ Q,
                                               const unsigned short* __restrict__ Kc,
                                               const float* __restrict__ lrs,
                                               float* __restrict__ amean) {
    __shared__ __attribute__((aligned(16))) unsigned short Qlds[16384];  // 2 x 16KB
    __shared__ float rslds[2][128];
    int t = threadIdx.x, lane = t & 63, w = t >> 6;
    int quad = lane >> 4, c = lane & 15;
    int bi = blockIdx.x;
    int hb = bi & 31, kt = bi >> 5, b = hb & 1;
    const unsigned short* kbase = Kc + (size_t)hb * 131072 + (size_t)(kt * 128 + w * 16) * 64;
    const unsigned short* qbase = Q + (size_t)hb * 131072;

    // K A-frags in registers (m=key=c, k=d)
    bf16x8 kf[2];
#pragma unroll
    for (int ks = 0; ks < 2; ++ks)
        kf[ks] = *(const bf16x8*)&kbase[c * 64 + ks * 32 + quad * 8];

    // prologue: stage chunk 0
#pragma unroll
    for (int i = 0; i < 2; ++i) {
        int ch = i * 512 + t;
        int row = ch >> 3, Bs = ch & 7;
        glds16(&qbase[row * 64 + ((Bs ^ (row & 7)) * 8)], (char*)Qlds + ch * 16);
    }
    if (t < 128) rslds[0][t] = lrs[hb * 2048 + t];

    f32x4 colacc = (f32x4){0.f, 0.f, 0.f, 0.f};

    for (int qc = 0; qc < 16; ++qc) {
        const unsigned short* Qb = Qlds + (qc & 1) * 8192;
        __syncthreads();
        if (qc < 15) {
            unsigned short* Qn = Qlds + ((qc + 1) & 1) * 8192;
#pragma unroll
            for (int i = 0; i < 2; ++i) {
                int ch = i * 512 + t;
                int row = ch >> 3, Bs = ch & 7;
                glds16(&qbase[(size_t)(qc + 1) * 8192 + row * 64 + ((Bs ^ (row & 7)) * 8)],
                       (char*)Qn + ch * 16);
            }
            if (t < 128) rslds[(qc + 1) & 1][t] = lrs[hb * 2048 + (qc + 1) * 128 + t];
        }
#pragma unroll
        for (int qs = 0; qs < 8; ++qs) {
            f32x4 st = (f32x4){0.f, 0.f, 0.f, 0.f};
#pragma unroll
            for (int ks = 0; ks < 2; ++ks) {
                bf16x8 qfr = *(const bf16x8*)&Qb[(qs * 16 + c) * 64 +
                                                 (((ks * 4 + quad) ^ (c & 7)) * 8)];
                st = __builtin_amdgcn_mfma_f32_16x16x32_bf16(kf[ks], qfr, st, 0, 0, 0);
            }
            float rv = rslds[qc & 1][qs * 16 + c];
#pragma unroll
            for (int r = 0; r < 4; ++r)
                colacc[r] += __builtin_amdgcn_exp2f(st[r] + rv);
        }
    }
    // reduce over q-lanes (c bits), then one atomic per key
#pragma unroll
    for (int r = 0; r < 4; ++r) {
        float v = colacc[r];
        v += __shfl_xor(v, 1);
        v += __shfl_xor(v, 2);
        v += __shfl_xor(v, 4);
        v += __shfl_xor(v, 8);
        if (c == 0)
            atomicAdd(&amean[b * 2048 + kt * 128 + w * 16 + quad * 4 + r], v);
    }
}

extern "C" void kernel_launch(void* const* d_in, const int* in_sizes, int n_in,
                              void* d_out, int out_size, void* d_ws, size_t ws_size,
                              hipStream_t stream) {
    const float* x = (const float*)d_in[0];
    const float* w_qkv = (const float*)d_in[1];
    const float* b_qkv = (const float*)d_in[2];
    const float* w_out = (const float*)d_in[3];
    const float* b_out = (const float*)d_in[4];
    float* out = (float*)d_out;
    float* amean = out + 4194304;

    unsigned short* ws = (unsigned short*)d_ws;
    unsigned short* x_bf = ws;                   // 4 Mi elems
    unsigned short* wqkvT = x_bf + 4194304;      // 3 Mi
    unsigned short* woutT = wqkvT + 3145728;     // 1 Mi
    unsigned short* q_bf = woutT + 1048576;      // 4 Mi  [HB][N][64], pre-scaled by EXP2SC
    unsigned short* k_bf = q_bf + 4194304;       // 4 Mi  [HB][N][64]
    unsigned short* vT_bf = k_bf + 4194304;      // 4 Mi  [HB][64][N]
    unsigned short* ctx_bf = vT_bf + 4194304;    // 4 Mi
    float* lrs = (float*)(ctx_bf + 4194304);     // 64 Ki floats

    k_prep<<<5121, 256, 0, stream>>>(x, x_bf, w_qkv, wqkvT, w_out, woutT, amean);
    k_gemm_qkv<<<dim3(24, 32), 256, 0, stream>>>(x_bf, wqkvT, b_qkv, q_bf, 4096, 3072, 1024);
    k_attn<<<512, 512, 0, stream>>>(q_bf, k_bf, vT_bf, ctx_bf, lrs);
    k_amean<<<512, 512, 0, stream>>>(q_bf, k_bf, lrs, amean);
    k_gemm_out<<<dim3(8, 64), 256, 0, stream>>>(ctx_bf, woutT, b_out, out, 4096, 1024, 1024);
}

// Round 6
// 221.617 us; speedup vs baseline: 1.0062x; 1.0062x over previous
//
#include <hip/hip_runtime.h>
#include <hip/hip_bf16.h>
#include <stdint.h>

#define B_ 2
#define N_ 2048
#define D_ 1024
#define H_ 16
#define DK 64

typedef __bf16 bf16x8 __attribute__((ext_vector_type(8)));
typedef short s16x4 __attribute__((ext_vector_type(4)));
typedef float f32x4 __attribute__((ext_vector_type(4)));

#define EXP2SC 0.18033688011112042f  // 0.125 * log2(e)

__device__ __forceinline__ unsigned short f2bf(float f) {
    unsigned int u = __float_as_uint(f);
    u = (u + 0x7FFFu + ((u >> 16) & 1u)) >> 16;
    return (unsigned short)u;
}

__device__ __forceinline__ short2 pkbf(float a, float b) {
    __hip_bfloat162 t = __float22bfloat162_rn(float2{a, b});
    return *(short2*)&t;
}

// async global->LDS, 16B per lane; lds dest must be wave-uniform base + lane*16
__device__ __forceinline__ void glds16(const void* g, void* l) {
    __builtin_amdgcn_global_load_lds(
        (const __attribute__((address_space(1))) void*)g,
        (__attribute__((address_space(3))) void*)l, 16, 0, 0);
}

// ---------------- fused prep: convert x, transpose both weights, zero amean ----------------
__global__ __launch_bounds__(256) void k_prep(const float* __restrict__ x,
                                              unsigned short* __restrict__ xb,
                                              const float* __restrict__ w_qkv,
                                              unsigned short* __restrict__ wqkvT,
                                              const float* __restrict__ w_out,
                                              unsigned short* __restrict__ woutT,
                                              float* __restrict__ amean) {
    __shared__ float tile[32][33];
    int blk = blockIdx.x, t = threadIdx.x;
    if (blk < 1024) {
        const float4* x4 = (const float4*)x;
        ushort4* o4 = (ushort4*)xb;
        int i = blk * 256 + t;
#pragma unroll
        for (int s = 0; s < 4; ++s, i += 262144) {
            float4 v = x4[i];
            ushort4 o;
            o.x = f2bf(v.x); o.y = f2bf(v.y); o.z = f2bf(v.z); o.w = f2bf(v.w);
            o4[i] = o;
        }
    } else if (blk < 4096) {
        int idx = blk - 1024;
        int c0 = (idx % 96) * 32, k0 = (idx / 96) * 32;
        int tx = t & 31, ty = t >> 5;
        for (int s = 0; s < 4; ++s)
            tile[ty + 8 * s][tx] = w_qkv[(size_t)(k0 + ty + 8 * s) * 3072 + c0 + tx];
        __syncthreads();
        for (int s = 0; s < 4; ++s)
            wqkvT[(size_t)(c0 + ty + 8 * s) * 1024 + k0 + tx] = f2bf(tile[tx][ty + 8 * s]);
    } else if (blk < 5120) {
        int idx = blk - 4096;
        int c0 = (idx % 32) * 32, k0 = (idx / 32) * 32;
        int tx = t & 31, ty = t >> 5;
        for (int s = 0; s < 4; ++s)
            tile[ty + 8 * s][tx] = w_out[(size_t)(k0 + ty + 8 * s) * 1024 + c0 + tx];
        __syncthreads();
        for (int s = 0; s < 4; ++s)
            woutT[(size_t)(c0 + ty + 8 * s) * 1024 + k0 + tx] = f2bf(tile[tx][ty + 8 * s]);
    } else {
#pragma unroll
        for (int s = 0; s < 16; ++s) amean[s * 256 + t] = 0.f;
    }
}

// ---------------- QKV GEMM: 128x128 tile; swizzled LDS; scatter q(pre-scaled),k,vT ----------
__global__ __launch_bounds__(256) void k_gemm_qkv(const unsigned short* __restrict__ A,
                                                  const unsigned short* __restrict__ BT,
                                                  const float* __restrict__ bias,
                                                  unsigned short* __restrict__ Cout,
                                                  int M, int Nn, int K) {
    __shared__ __attribute__((aligned(16))) unsigned short Alds[128 * 64];
    __shared__ __attribute__((aligned(16))) unsigned short Blds[128 * 64];
    int t = threadIdx.x;
    int lane = t & 63, w = t >> 6;
    int quad = lane >> 4, c = lane & 15;
    int wm = w >> 1, wn = w & 1;
    int bi = blockIdx.y, bj = blockIdx.x;
    const unsigned short* Abase = A + (size_t)(bi * 128) * K;
    const unsigned short* Bbase = BT + (size_t)(bj * 128) * K;

    f32x4 acc[4][4];
#pragma unroll
    for (int mf = 0; mf < 4; ++mf)
#pragma unroll
        for (int nf = 0; nf < 4; ++nf)
            acc[mf][nf] = (f32x4){0.f, 0.f, 0.f, 0.f};

    for (int k0 = 0; k0 < K; k0 += 64) {
        __syncthreads();
#pragma unroll
        for (int i = 0; i < 4; ++i) {
            int ch = i * 256 + t;
            int row = ch >> 3, kc = (ch & 7) ^ (row & 7);
            glds16(&Abase[(size_t)row * K + k0 + kc * 8], (char*)Alds + ch * 16);
            glds16(&Bbase[(size_t)row * K + k0 + kc * 8], (char*)Blds + ch * 16);
        }
        __syncthreads();
#pragma unroll
        for (int ks = 0; ks < 2; ++ks) {
            bf16x8 af[4], bfr[4];
#pragma unroll
            for (int mf = 0; mf < 4; ++mf)
                af[mf] = *(const bf16x8*)&Alds[(wm * 64 + mf * 16 + c) * 64 +
                                               (((ks * 4 + quad) ^ (c & 7)) * 8)];
#pragma unroll
            for (int nf = 0; nf < 4; ++nf)
                bfr[nf] = *(const bf16x8*)&Blds[(wn * 64 + nf * 16 + c) * 64 +
                                                (((ks * 4 + quad) ^ (c & 7)) * 8)];
#pragma unroll
            for (int mf = 0; mf < 4; ++mf)
#pragma unroll
                for (int nf = 0; nf < 4; ++nf)
                    acc[mf][nf] = __builtin_amdgcn_mfma_f32_16x16x32_bf16(af[mf], bfr[nf],
                                                                          acc[mf][nf], 0, 0, 0);
        }
    }

#pragma unroll
    for (int mf = 0; mf < 4; ++mf)
#pragma unroll
        for (int nf = 0; nf < 4; ++nf) {
            int j = bj * 128 + wn * 64 + nf * 16 + c;
            float bv = bias[j];
            int h = j / 192, r2 = j % 192;
            int which = r2 >> 6, d = r2 & 63;
#pragma unroll
            for (int r = 0; r < 4; ++r) {
                int i = bi * 128 + wm * 64 + mf * 16 + quad * 4 + r;
                float v = acc[mf][nf][r] + bv;
                if (which == 0) v *= EXP2SC;  // fold softmax scale + log2e into Q
                int b = i >> 11, n = i & 2047;
                size_t dst;
                if (which < 2)
                    dst = (size_t)which * 4194304 + (((size_t)(h * 2 + b) * 2048 + n) * 64 + d);
                else
                    dst = (size_t)2 * 4194304 + (((size_t)(h * 2 + b) * 64 + d) * 2048 + n);
                Cout[dst] = f2bf(v);
            }
        }
}

// ---------------- out-proj GEMM: 64x128 tile, swizzled LDS, fp32 out ----------------
__global__ __launch_bounds__(256) void k_gemm_out(const unsigned short* __restrict__ A,
                                                  const unsigned short* __restrict__ BT,
                                                  const float* __restrict__ bias,
                                                  float* __restrict__ C,
                                                  int M, int Nn, int K) {
    __shared__ __attribute__((aligned(16))) unsigned short Alds[64 * 64];
    __shared__ __attribute__((aligned(16))) unsigned short Blds[128 * 64];
    int t = threadIdx.x;
    int lane = t & 63, w = t >> 6;
    int quad = lane >> 4, c = lane & 15;
    int wm = w >> 1, wn = w & 1;
    int bi = blockIdx.y, bj = blockIdx.x;
    const unsigned short* Abase = A + (size_t)(bi * 64) * K;
    const unsigned short* Bbase = BT + (size_t)(bj * 128) * K;

    f32x4 acc[2][4];
#pragma unroll
    for (int mf = 0; mf < 2; ++mf)
#pragma unroll
        for (int nf = 0; nf < 4; ++nf)
            acc[mf][nf] = (f32x4){0.f, 0.f, 0.f, 0.f};

    for (int k0 = 0; k0 < K; k0 += 64) {
        __syncthreads();
#pragma unroll
        for (int i = 0; i < 2; ++i) {
            int ch = i * 256 + t;
            int row = ch >> 3, kc = (ch & 7) ^ (row & 7);
            glds16(&Abase[(size_t)row * K + k0 + kc * 8], (char*)Alds + ch * 16);
        }
#pragma unroll
        for (int i = 0; i < 4; ++i) {
            int ch = i * 256 + t;
            int row = ch >> 3, kc = (ch & 7) ^ (row & 7);
            glds16(&Bbase[(size_t)row * K + k0 + kc * 8], (char*)Blds + ch * 16);
        }
        __syncthreads();
#pragma unroll
        for (int ks = 0; ks < 2; ++ks) {
            bf16x8 af[2], bfr[4];
#pragma unroll
            for (int mf = 0; mf < 2; ++mf)
                af[mf] = *(const bf16x8*)&Alds[(wm * 32 + mf * 16 + c) * 64 +
                                               (((ks * 4 + quad) ^ (c & 7)) * 8)];
#pragma unroll
            for (int nf = 0; nf < 4; ++nf)
                bfr[nf] = *(const bf16x8*)&Blds[(wn * 64 + nf * 16 + c) * 64 +
                                                (((ks * 4 + quad) ^ (c & 7)) * 8)];
#pragma unroll
            for (int mf = 0; mf < 2; ++mf)
#pragma unroll
                for (int nf = 0; nf < 4; ++nf)
                    acc[mf][nf] = __builtin_amdgcn_mfma_f32_16x16x32_bf16(af[mf], bfr[nf],
                                                                          acc[mf][nf], 0, 0, 0);
        }
    }

#pragma unroll
    for (int mf = 0; mf < 2; ++mf)
#pragma unroll
        for (int nf = 0; nf < 4; ++nf) {
            int j = bj * 128 + wn * 64 + nf * 16 + c;
            float bv = bias[j];
#pragma unroll
            for (int r = 0; r < 4; ++r) {
                int i = bi * 64 + wm * 32 + mf * 16 + quad * 4 + r;
                C[(size_t)i * Nn + j] = acc[mf][nf][r] + bv;
            }
        }
}

// ---------------- attention: 8 waves x 32 q-rows (2 tiles), 256-q blocks, grid 256 ----------
// hb = bi&31 (XCD-clustered), qt = bi>>5 in [0,8). K/V frag reads amortized over 2 q-tiles.
__global__ __launch_bounds__(512) void k_attn(const unsigned short* __restrict__ Q,
                                              const unsigned short* __restrict__ Kc,
                                              const unsigned short* __restrict__ VT,
                                              unsigned short* __restrict__ ctx,
                                              float* __restrict__ lrs_out) {
    __shared__ __attribute__((aligned(16))) unsigned short lds[16384];  // 2 x (K 8KB + V 8KB)
    int t = threadIdx.x, lane = t & 63, w = t >> 6;
    int quad = lane >> 4, c = lane & 15;
    int bi = blockIdx.x;
    int hb = bi & 31, qt = bi >> 5;
    int h = hb >> 1, b = hb & 1;
    const unsigned short* qbase = Q + (size_t)hb * 131072 + (size_t)(qt * 256 + w * 32) * 64;
    const unsigned short* kbase = Kc + (size_t)hb * 131072;
    const unsigned short* vtbase = VT + (size_t)hb * 131072;

    int srow = t >> 3, sB = t & 7;
    int sgoff = srow * 64 + ((sB ^ (srow & 7)) * 8);
    int vgoff = srow * 2048 + ((sB ^ (srow & 7)) * 8);

    // Q fragments: 2 q-subtiles x 2 k-halves (pre-scaled by EXP2SC in QKV epilogue)
    bf16x8 qf[2][2];
#pragma unroll
    for (int qs = 0; qs < 2; ++qs)
#pragma unroll
        for (int ks = 0; ks < 2; ++ks)
            qf[qs][ks] = *(const bf16x8*)&qbase[(qs * 16 + c) * 64 + ks * 32 + quad * 8];

    // prologue: stage chunk 0 into buffer 0
    glds16(&kbase[sgoff], (char*)lds + t * 16);
    glds16(&vtbase[vgoff], (char*)(lds + 4096) + t * 16);

    f32x4 acc[2][4];
#pragma unroll
    for (int qs = 0; qs < 2; ++qs)
#pragma unroll
        for (int ds = 0; ds < 4; ++ds) acc[qs][ds] = (f32x4){0.f, 0.f, 0.f, 0.f};
    float lsum[2] = {0.f, 0.f};

    for (int kb = 0; kb < 32; ++kb) {
        const unsigned short* Kb = lds + (kb & 1) * 8192;
        const unsigned short* Vb = Kb + 4096;
        __syncthreads();
        if (kb < 31) {
            unsigned short* Kn = lds + ((kb + 1) & 1) * 8192;
            glds16(&kbase[(size_t)(kb + 1) * 4096 + sgoff], (char*)Kn + t * 16);
            glds16(&vtbase[(size_t)(kb + 1) * 64 + vgoff], (char*)(Kn + 4096) + t * 16);
        }

        // S^T tiles [ksub][qs]: row=key=quad*4+r, col=q=c; K-frag shared across qs
        f32x4 st[4][2];
#pragma unroll
        for (int ksub = 0; ksub < 4; ++ksub)
#pragma unroll
            for (int qs = 0; qs < 2; ++qs) st[ksub][qs] = (f32x4){0.f, 0.f, 0.f, 0.f};
#pragma unroll
        for (int ks = 0; ks < 2; ++ks)
#pragma unroll
            for (int ksub = 0; ksub < 4; ++ksub) {
                bf16x8 kf = *(const bf16x8*)&Kb[(ksub * 16 + c) * 64 +
                                                (((ks * 4 + quad) ^ (c & 7)) * 8)];
#pragma unroll
                for (int qs = 0; qs < 2; ++qs)
                    st[ksub][qs] =
                        __builtin_amdgcn_mfma_f32_16x16x32_bf16(kf, qf[qs][ks], st[ksub][qs],
                                                                0, 0, 0);
            }
        // exp2 in-register -> PV A-frags; V-frag reads shared across qs
#pragma unroll
        for (int ksub = 0; ksub < 4; ++ksub) {
            s16x4 pf[2];
#pragma unroll
            for (int qs = 0; qs < 2; ++qs) {
                float p0 = __builtin_amdgcn_exp2f(st[ksub][qs][0]);
                float p1 = __builtin_amdgcn_exp2f(st[ksub][qs][1]);
                float p2 = __builtin_amdgcn_exp2f(st[ksub][qs][2]);
                float p3 = __builtin_amdgcn_exp2f(st[ksub][qs][3]);
                lsum[qs] += (p0 + p1) + (p2 + p3);
                short2 lo = pkbf(p0, p1), hi = pkbf(p2, p3);
                pf[qs] = (s16x4){lo.x, lo.y, hi.x, hi.y};
            }
            s16x4 vf[4];
#pragma unroll
            for (int ds = 0; ds < 4; ++ds) {
                int row = ds * 16 + c;
                vf[ds] = *(const s16x4*)&Vb[row * 64 +
                                            (((2 * ksub + (quad >> 1)) ^ (row & 7)) * 8) +
                                            (quad & 1) * 4];
            }
#pragma unroll
            for (int qs = 0; qs < 2; ++qs)
#pragma unroll
                for (int ds = 0; ds < 4; ++ds)
                    acc[qs][ds] = __builtin_amdgcn_mfma_f32_16x16x16bf16_1k(pf[qs], vf[ds],
                                                                            acc[qs][ds], 0, 0, 0);
        }
    }

#pragma unroll
    for (int qs = 0; qs < 2; ++qs) {
        float v = lsum[qs];
        v += __shfl_xor(v, 16);
        v += __shfl_xor(v, 32);
        if (lane < 16)
            lrs_out[hb * 2048 + qt * 256 + w * 32 + qs * 16 + c] =
                -(__builtin_amdgcn_logf(v) + 15.0f);  // log2(1/(l*H*N))
        float linv = 1.0f / v;
        float ir[4];
#pragma unroll
        for (int r = 0; r < 4; ++r) ir[r] = __shfl(linv, quad * 4 + r);
#pragma unroll
        for (int ds = 0; ds < 4; ++ds)
#pragma unroll
            for (int r = 0; r < 4; ++r) {
                int n = qt * 256 + w * 32 + qs * 16 + quad * 4 + r;
                ctx[((size_t)(b * 2048 + n)) * 1024 + h * 64 + ds * 16 + c] =
                    f2bf(acc[qs][ds][r] * ir[r]);
            }
    }
}

// ---------------- attn_mean: 8 waves x 32 keys (2 tiles), 256-key blocks, grid 256 ----------
__global__ __launch_bounds__(512) void k_amean(const unsigned short* __restrict__ Q,
                                               const unsigned short* __restrict__ Kc,
                                               const float* __restrict__ lrs,
                                               float* __restrict__ amean) {
    __shared__ __attribute__((aligned(16))) unsigned short Qlds[16384];  // 2 x 16KB
    __shared__ float rslds[2][128];
    int t = threadIdx.x, lane = t & 63, w = t >> 6;
    int quad = lane >> 4, c = lane & 15;
    int bi = blockIdx.x;
    int hb = bi & 31, kt = bi >> 5, b = hb & 1;
    const unsigned short* kbase = Kc + (size_t)hb * 131072 + (size_t)(kt * 256 + w * 32) * 64;
    const unsigned short* qbase = Q + (size_t)hb * 131072;

    // K A-frags in registers: 2 key-subtiles x 2 k-halves (m=key=c, k=d)
    bf16x8 kf[2][2];
#pragma unroll
    for (int ksub = 0; ksub < 2; ++ksub)
#pragma unroll
        for (int ks = 0; ks < 2; ++ks)
            kf[ksub][ks] = *(const bf16x8*)&kbase[(ksub * 16 + c) * 64 + ks * 32 + quad * 8];

    // prologue: stage chunk 0
#pragma unroll
    for (int i = 0; i < 2; ++i) {
        int ch = i * 512 + t;
        int row = ch >> 3, Bs = ch & 7;
        glds16(&qbase[row * 64 + ((Bs ^ (row & 7)) * 8)], (char*)Qlds + ch * 16);
    }
    if (t < 128) rslds[0][t] = lrs[hb * 2048 + t];

    f32x4 colacc[2];
    colacc[0] = (f32x4){0.f, 0.f, 0.f, 0.f};
    colacc[1] = (f32x4){0.f, 0.f, 0.f, 0.f};

    for (int qc = 0; qc < 16; ++qc) {
        const unsigned short* Qb = Qlds + (qc & 1) * 8192;
        __syncthreads();
        if (qc < 15) {
            unsigned short* Qn = Qlds + ((qc + 1) & 1) * 8192;
#pragma unroll
            for (int i = 0; i < 2; ++i) {
                int ch = i * 512 + t;
                int row = ch >> 3, Bs = ch & 7;
                glds16(&qbase[(size_t)(qc + 1) * 8192 + row * 64 + ((Bs ^ (row & 7)) * 8)],
                       (char*)Qn + ch * 16);
            }
            if (t < 128) rslds[(qc + 1) & 1][t] = lrs[hb * 2048 + (qc + 1) * 128 + t];
        }
#pragma unroll
        for (int qs = 0; qs < 8; ++qs) {
            f32x4 st[2];
            st[0] = (f32x4){0.f, 0.f, 0.f, 0.f};
            st[1] = (f32x4){0.f, 0.f, 0.f, 0.f};
#pragma unroll
            for (int ks = 0; ks < 2; ++ks) {
                bf16x8 qfr = *(const bf16x8*)&Qb[(qs * 16 + c) * 64 +
                                                 (((ks * 4 + quad) ^ (c & 7)) * 8)];
#pragma unroll
                for (int ksub = 0; ksub < 2; ++ksub)
                    st[ksub] = __builtin_amdgcn_mfma_f32_16x16x32_bf16(kf[ksub][ks], qfr,
                                                                       st[ksub], 0, 0, 0);
            }
            float rv = rslds[qc & 1][qs * 16 + c];
#pragma unroll
            for (int ksub = 0; ksub < 2; ++ksub)
#pragma unroll
                for (int r = 0; r < 4; ++r)
                    colacc[ksub][r] += __builtin_amdgcn_exp2f(st[ksub][r] + rv);
        }
    }
    // reduce over q-lanes (c bits), then one atomic per key
#pragma unroll
    for (int ksub = 0; ksub < 2; ++ksub)
#pragma unroll
        for (int r = 0; r < 4; ++r) {
            float v = colacc[ksub][r];
            v += __shfl_xor(v, 1);
            v += __shfl_xor(v, 2);
            v += __shfl_xor(v, 4);
            v += __shfl_xor(v, 8);
            if (c == 0)
                atomicAdd(&amean[b * 2048 + kt * 256 + w * 32 + ksub * 16 + quad * 4 + r], v);
        }
}

extern "C" void kernel_launch(void* const* d_in, const int* in_sizes, int n_in,
                              void* d_out, int out_size, void* d_ws, size_t ws_size,
                              hipStream_t stream) {
    const float* x = (const float*)d_in[0];
    const float* w_qkv = (const float*)d_in[1];
    const float* b_qkv = (const float*)d_in[2];
    const float* w_out = (const float*)d_in[3];
    const float* b_out = (const float*)d_in[4];
    float* out = (float*)d_out;
    float* amean = out + 4194304;

    unsigned short* ws = (unsigned short*)d_ws;
    unsigned short* x_bf = ws;                   // 4 Mi elems
    unsigned short* wqkvT = x_bf + 4194304;      // 3 Mi
    unsigned short* woutT = wqkvT + 3145728;     // 1 Mi
    unsigned short* q_bf = woutT + 1048576;      // 4 Mi  [HB][N][64], pre-scaled by EXP2SC
    unsigned short* k_bf = q_bf + 4194304;       // 4 Mi  [HB][N][64]
    unsigned short* vT_bf = k_bf + 4194304;      // 4 Mi  [HB][64][N]
    unsigned short* ctx_bf = vT_bf + 4194304;    // 4 Mi
    float* lrs = (float*)(ctx_bf + 4194304);     // 64 Ki floats

    k_prep<<<5121, 256, 0, stream>>>(x, x_bf, w_qkv, wqkvT, w_out, woutT, amean);
    k_gemm_qkv<<<dim3(24, 32), 256, 0, stream>>>(x_bf, wqkvT, b_qkv, q_bf, 4096, 3072, 1024);
    k_attn<<<256, 512, 0, stream>>>(q_bf, k_bf, vT_bf, ctx_bf, lrs);
    k_amean<<<256, 512, 0, stream>>>(q_bf, k_bf, lrs, amean);
    k_gemm_out<<<dim3(8, 64), 256, 0, stream>>>(ctx_bf, woutT, b_out, out, 4096, 1024, 1024);
}

// Round 7
// 208.846 us; speedup vs baseline: 1.0677x; 1.0611x over previous
//
#include <hip/hip_runtime.h>
#include <hip/hip_bf16.h>
#include <stdint.h>

#define B_ 2
#define N_ 2048
#define D_ 1024
#define H_ 16
#define DK 64

typedef __bf16 bf16x8 __attribute__((ext_vector_type(8)));
typedef short s16x4 __attribute__((ext_vector_type(4)));
typedef float f32x4 __attribute__((ext_vector_type(4)));

#define EXP2SC 0.18033688011112042f  // 0.125 * log2(e)

__device__ __forceinline__ unsigned short f2bf(float f) {
    unsigned int u = __float_as_uint(f);
    u = (u + 0x7FFFu + ((u >> 16) & 1u)) >> 16;
    return (unsigned short)u;
}

__device__ __forceinline__ short2 pkbf(float a, float b) {
    __hip_bfloat162 t = __float22bfloat162_rn(float2{a, b});
    return *(short2*)&t;
}

// async global->LDS, 16B per lane; lds dest must be wave-uniform base + lane*16
__device__ __forceinline__ void glds16(const void* g, void* l) {
    __builtin_amdgcn_global_load_lds(
        (const __attribute__((address_space(1))) void*)g,
        (__attribute__((address_space(3))) void*)l, 16, 0, 0);
}

// ---------------- fused prep: convert x, transpose both weights, zero amean ----------------
__global__ __launch_bounds__(256) void k_prep(const float* __restrict__ x,
                                              unsigned short* __restrict__ xb,
                                              const float* __restrict__ w_qkv,
                                              unsigned short* __restrict__ wqkvT,
                                              const float* __restrict__ w_out,
                                              unsigned short* __restrict__ woutT,
                                              float* __restrict__ amean) {
    __shared__ float tile[32][33];
    int blk = blockIdx.x, t = threadIdx.x;
    if (blk < 1024) {
        const float4* x4 = (const float4*)x;
        ushort4* o4 = (ushort4*)xb;
        int i = blk * 256 + t;
#pragma unroll
        for (int s = 0; s < 4; ++s, i += 262144) {
            float4 v = x4[i];
            ushort4 o;
            o.x = f2bf(v.x); o.y = f2bf(v.y); o.z = f2bf(v.z); o.w = f2bf(v.w);
            o4[i] = o;
        }
    } else if (blk < 4096) {
        int idx = blk - 1024;
        int c0 = (idx % 96) * 32, k0 = (idx / 96) * 32;
        int tx = t & 31, ty = t >> 5;
        for (int s = 0; s < 4; ++s)
            tile[ty + 8 * s][tx] = w_qkv[(size_t)(k0 + ty + 8 * s) * 3072 + c0 + tx];
        __syncthreads();
        for (int s = 0; s < 4; ++s)
            wqkvT[(size_t)(c0 + ty + 8 * s) * 1024 + k0 + tx] = f2bf(tile[tx][ty + 8 * s]);
    } else if (blk < 5120) {
        int idx = blk - 4096;
        int c0 = (idx % 32) * 32, k0 = (idx / 32) * 32;
        int tx = t & 31, ty = t >> 5;
        for (int s = 0; s < 4; ++s)
            tile[ty + 8 * s][tx] = w_out[(size_t)(k0 + ty + 8 * s) * 1024 + c0 + tx];
        __syncthreads();
        for (int s = 0; s < 4; ++s)
            woutT[(size_t)(c0 + ty + 8 * s) * 1024 + k0 + tx] = f2bf(tile[tx][ty + 8 * s]);
    } else {
#pragma unroll
        for (int s = 0; s < 16; ++s) amean[s * 256 + t] = 0.f;
    }
}

// ---------------- QKV GEMM: 128x128 tile; ping-pong dbuf; swizzled LDS; scatter epilogue ----
__global__ __launch_bounds__(256) void k_gemm_qkv(const unsigned short* __restrict__ A,
                                                  const unsigned short* __restrict__ BT,
                                                  const float* __restrict__ bias,
                                                  unsigned short* __restrict__ Cout,
                                                  int M, int Nn, int K) {
    // 2 buffers x (A 8192 + B 8192) elems = 64 KB
    __shared__ __attribute__((aligned(16))) unsigned short lds[32768];
    int t = threadIdx.x;
    int lane = t & 63, w = t >> 6;
    int quad = lane >> 4, c = lane & 15;
    int wm = w >> 1, wn = w & 1;
    int bi = blockIdx.y, bj = blockIdx.x;
    const unsigned short* Abase = A + (size_t)(bi * 128) * K;
    const unsigned short* Bbase = BT + (size_t)(bj * 128) * K;

    f32x4 acc[4][4];
#pragma unroll
    for (int mf = 0; mf < 4; ++mf)
#pragma unroll
        for (int nf = 0; nf < 4; ++nf)
            acc[mf][nf] = (f32x4){0.f, 0.f, 0.f, 0.f};

    // stage K-chunk k0 into buffer p (swizzled: LDS slot ch holds global block (ch&7)^(row&7))
    auto stage = [&](int k0, int p) {
        unsigned short* Ab = lds + p * 16384;
        unsigned short* Bb = Ab + 8192;
#pragma unroll
        for (int i = 0; i < 4; ++i) {
            int ch = i * 256 + t;  // 0..1023
            int row = ch >> 3, kc = (ch & 7) ^ (row & 7);
            glds16(&Abase[(size_t)row * K + k0 + kc * 8], (char*)Ab + ch * 16);
            glds16(&Bbase[(size_t)row * K + k0 + kc * 8], (char*)Bb + ch * 16);
        }
    };
    stage(0, 0);

    for (int kb = 0; kb < 16; ++kb) {
        __syncthreads();  // drains glds for buffer kb&1; protects buffer (kb+1)&1 reuse
        if (kb < 15) stage((kb + 1) * 64, (kb + 1) & 1);
        const unsigned short* Ab = lds + (kb & 1) * 16384;
        const unsigned short* Bb = Ab + 8192;
#pragma unroll
        for (int ks = 0; ks < 2; ++ks) {
            bf16x8 af[4], bfr[4];
#pragma unroll
            for (int mf = 0; mf < 4; ++mf)
                af[mf] = *(const bf16x8*)&Ab[(wm * 64 + mf * 16 + c) * 64 +
                                             (((ks * 4 + quad) ^ (c & 7)) * 8)];
#pragma unroll
            for (int nf = 0; nf < 4; ++nf)
                bfr[nf] = *(const bf16x8*)&Bb[(wn * 64 + nf * 16 + c) * 64 +
                                              (((ks * 4 + quad) ^ (c & 7)) * 8)];
#pragma unroll
            for (int mf = 0; mf < 4; ++mf)
#pragma unroll
                for (int nf = 0; nf < 4; ++nf)
                    acc[mf][nf] = __builtin_amdgcn_mfma_f32_16x16x32_bf16(af[mf], bfr[nf],
                                                                          acc[mf][nf], 0, 0, 0);
        }
    }

#pragma unroll
    for (int mf = 0; mf < 4; ++mf)
#pragma unroll
        for (int nf = 0; nf < 4; ++nf) {
            int j = bj * 128 + wn * 64 + nf * 16 + c;
            float bv = bias[j];
            int h = j / 192, r2 = j % 192;
            int which = r2 >> 6, d = r2 & 63;
#pragma unroll
            for (int r = 0; r < 4; ++r) {
                int i = bi * 128 + wm * 64 + mf * 16 + quad * 4 + r;
                float v = acc[mf][nf][r] + bv;
                if (which == 0) v *= EXP2SC;  // fold softmax scale + log2e into Q
                int b = i >> 11, n = i & 2047;
                size_t dst;
                if (which < 2)
                    dst = (size_t)which * 4194304 + (((size_t)(h * 2 + b) * 2048 + n) * 64 + d);
                else
                    dst = (size_t)2 * 4194304 + (((size_t)(h * 2 + b) * 64 + d) * 2048 + n);
                Cout[dst] = f2bf(v);
            }
        }
}

// ---------------- out-proj GEMM: 64x128 tile, ping-pong dbuf, swizzled LDS, fp32 out --------
__global__ __launch_bounds__(256) void k_gemm_out(const unsigned short* __restrict__ A,
                                                  const unsigned short* __restrict__ BT,
                                                  const float* __restrict__ bias,
                                                  float* __restrict__ C,
                                                  int M, int Nn, int K) {
    // 2 buffers x (A 4096 + B 8192) elems = 48 KB
    __shared__ __attribute__((aligned(16))) unsigned short lds[24576];
    int t = threadIdx.x;
    int lane = t & 63, w = t >> 6;
    int quad = lane >> 4, c = lane & 15;
    int wm = w >> 1, wn = w & 1;
    int bi = blockIdx.y, bj = blockIdx.x;
    const unsigned short* Abase = A + (size_t)(bi * 64) * K;
    const unsigned short* Bbase = BT + (size_t)(bj * 128) * K;

    f32x4 acc[2][4];
#pragma unroll
    for (int mf = 0; mf < 2; ++mf)
#pragma unroll
        for (int nf = 0; nf < 4; ++nf)
            acc[mf][nf] = (f32x4){0.f, 0.f, 0.f, 0.f};

    auto stage = [&](int k0, int p) {
        unsigned short* Ab = lds + p * 12288;
        unsigned short* Bb = Ab + 4096;
#pragma unroll
        for (int i = 0; i < 2; ++i) {
            int ch = i * 256 + t;  // 0..511
            int row = ch >> 3, kc = (ch & 7) ^ (row & 7);
            glds16(&Abase[(size_t)row * K + k0 + kc * 8], (char*)Ab + ch * 16);
        }
#pragma unroll
        for (int i = 0; i < 4; ++i) {
            int ch = i * 256 + t;  // 0..1023
            int row = ch >> 3, kc = (ch & 7) ^ (row & 7);
            glds16(&Bbase[(size_t)row * K + k0 + kc * 8], (char*)Bb + ch * 16);
        }
    };
    stage(0, 0);

    for (int kb = 0; kb < 16; ++kb) {
        __syncthreads();
        if (kb < 15) stage((kb + 1) * 64, (kb + 1) & 1);
        const unsigned short* Ab = lds + (kb & 1) * 12288;
        const unsigned short* Bb = Ab + 4096;
#pragma unroll
        for (int ks = 0; ks < 2; ++ks) {
            bf16x8 af[2], bfr[4];
#pragma unroll
            for (int mf = 0; mf < 2; ++mf)
                af[mf] = *(const bf16x8*)&Ab[(wm * 32 + mf * 16 + c) * 64 +
                                             (((ks * 4 + quad) ^ (c & 7)) * 8)];
#pragma unroll
            for (int nf = 0; nf < 4; ++nf)
                bfr[nf] = *(const bf16x8*)&Bb[(wn * 64 + nf * 16 + c) * 64 +
                                              (((ks * 4 + quad) ^ (c & 7)) * 8)];
#pragma unroll
            for (int mf = 0; mf < 2; ++mf)
#pragma unroll
                for (int nf = 0; nf < 4; ++nf)
                    acc[mf][nf] = __builtin_amdgcn_mfma_f32_16x16x32_bf16(af[mf], bfr[nf],
                                                                          acc[mf][nf], 0, 0, 0);
        }
    }

#pragma unroll
    for (int mf = 0; mf < 2; ++mf)
#pragma unroll
        for (int nf = 0; nf < 4; ++nf) {
            int j = bj * 128 + wn * 64 + nf * 16 + c;
            float bv = bias[j];
#pragma unroll
            for (int r = 0; r < 4; ++r) {
                int i = bi * 64 + wm * 32 + mf * 16 + quad * 4 + r;
                C[(size_t)i * Nn + j] = acc[mf][nf][r] + bv;
            }
        }
}

// ---------------- attention: 8 waves x 32 q-rows (2 tiles), 256-q blocks, grid 256 ----------
// hb = bi&31 (XCD-clustered), qt = bi>>5 in [0,8). K/V frag reads amortized over 2 q-tiles.
__global__ __launch_bounds__(512) void k_attn(const unsigned short* __restrict__ Q,
                                              const unsigned short* __restrict__ Kc,
                                              const unsigned short* __restrict__ VT,
                                              unsigned short* __restrict__ ctx,
                                              float* __restrict__ lrs_out) {
    __shared__ __attribute__((aligned(16))) unsigned short lds[16384];  // 2 x (K 8KB + V 8KB)
    int t = threadIdx.x, lane = t & 63, w = t >> 6;
    int quad = lane >> 4, c = lane & 15;
    int bi = blockIdx.x;
    int hb = bi & 31, qt = bi >> 5;
    int h = hb >> 1, b = hb & 1;
    const unsigned short* qbase = Q + (size_t)hb * 131072 + (size_t)(qt * 256 + w * 32) * 64;
    const unsigned short* kbase = Kc + (size_t)hb * 131072;
    const unsigned short* vtbase = VT + (size_t)hb * 131072;

    int srow = t >> 3, sB = t & 7;
    int sgoff = srow * 64 + ((sB ^ (srow & 7)) * 8);
    int vgoff = srow * 2048 + ((sB ^ (srow & 7)) * 8);

    // Q fragments: 2 q-subtiles x 2 k-halves (pre-scaled by EXP2SC in QKV epilogue)
    bf16x8 qf[2][2];
#pragma unroll
    for (int qs = 0; qs < 2; ++qs)
#pragma unroll
        for (int ks = 0; ks < 2; ++ks)
            qf[qs][ks] = *(const bf16x8*)&qbase[(qs * 16 + c) * 64 + ks * 32 + quad * 8];

    // prologue: stage chunk 0 into buffer 0
    glds16(&kbase[sgoff], (char*)lds + t * 16);
    glds16(&vtbase[vgoff], (char*)(lds + 4096) + t * 16);

    f32x4 acc[2][4];
#pragma unroll
    for (int qs = 0; qs < 2; ++qs)
#pragma unroll
        for (int ds = 0; ds < 4; ++ds) acc[qs][ds] = (f32x4){0.f, 0.f, 0.f, 0.f};
    float lsum[2] = {0.f, 0.f};

    for (int kb = 0; kb < 32; ++kb) {
        const unsigned short* Kb = lds + (kb & 1) * 8192;
        const unsigned short* Vb = Kb + 4096;
        __syncthreads();
        if (kb < 31) {
            unsigned short* Kn = lds + ((kb + 1) & 1) * 8192;
            glds16(&kbase[(size_t)(kb + 1) * 4096 + sgoff], (char*)Kn + t * 16);
            glds16(&vtbase[(size_t)(kb + 1) * 64 + vgoff], (char*)(Kn + 4096) + t * 16);
        }

        // S^T tiles [ksub][qs]: row=key=quad*4+r, col=q=c; K-frag shared across qs
        f32x4 st[4][2];
#pragma unroll
        for (int ksub = 0; ksub < 4; ++ksub)
#pragma unroll
            for (int qs = 0; qs < 2; ++qs) st[ksub][qs] = (f32x4){0.f, 0.f, 0.f, 0.f};
#pragma unroll
        for (int ks = 0; ks < 2; ++ks)
#pragma unroll
            for (int ksub = 0; ksub < 4; ++ksub) {
                bf16x8 kf = *(const bf16x8*)&Kb[(ksub * 16 + c) * 64 +
                                                (((ks * 4 + quad) ^ (c & 7)) * 8)];
#pragma unroll
                for (int qs = 0; qs < 2; ++qs)
                    st[ksub][qs] =
                        __builtin_amdgcn_mfma_f32_16x16x32_bf16(kf, qf[qs][ks], st[ksub][qs],
                                                                0, 0, 0);
            }
        // exp2 in-register -> PV A-frags; V-frag reads shared across qs
#pragma unroll
        for (int ksub = 0; ksub < 4; ++ksub) {
            s16x4 pf[2];
#pragma unroll
            for (int qs = 0; qs < 2; ++qs) {
                float p0 = __builtin_amdgcn_exp2f(st[ksub][qs][0]);
                float p1 = __builtin_amdgcn_exp2f(st[ksub][qs][1]);
                float p2 = __builtin_amdgcn_exp2f(st[ksub][qs][2]);
                float p3 = __builtin_amdgcn_exp2f(st[ksub][qs][3]);
                lsum[qs] += (p0 + p1) + (p2 + p3);
                short2 lo = pkbf(p0, p1), hi = pkbf(p2, p3);
                pf[qs] = (s16x4){lo.x, lo.y, hi.x, hi.y};
            }
            s16x4 vf[4];
#pragma unroll
            for (int ds = 0; ds < 4; ++ds) {
                int row = ds * 16 + c;
                vf[ds] = *(const s16x4*)&Vb[row * 64 +
                                            (((2 * ksub + (quad >> 1)) ^ (row & 7)) * 8) +
                                            (quad & 1) * 4];
            }
#pragma unroll
            for (int qs = 0; qs < 2; ++qs)
#pragma unroll
                for (int ds = 0; ds < 4; ++ds)
                    acc[qs][ds] = __builtin_amdgcn_mfma_f32_16x16x16bf16_1k(pf[qs], vf[ds],
                                                                            acc[qs][ds], 0, 0, 0);
        }
    }

#pragma unroll
    for (int qs = 0; qs < 2; ++qs) {
        float v = lsum[qs];
        v += __shfl_xor(v, 16);
        v += __shfl_xor(v, 32);
        if (lane < 16)
            lrs_out[hb * 2048 + qt * 256 + w * 32 + qs * 16 + c] =
                -(__builtin_amdgcn_logf(v) + 15.0f);  // log2(1/(l*H*N))
        float linv = 1.0f / v;
        float ir[4];
#pragma unroll
        for (int r = 0; r < 4; ++r) ir[r] = __shfl(linv, quad * 4 + r);
#pragma unroll
        for (int ds = 0; ds < 4; ++ds)
#pragma unroll
            for (int r = 0; r < 4; ++r) {
                int n = qt * 256 + w * 32 + qs * 16 + quad * 4 + r;
                ctx[((size_t)(b * 2048 + n)) * 1024 + h * 64 + ds * 16 + c] =
                    f2bf(acc[qs][ds][r] * ir[r]);
            }
    }
}

// ---------------- attn_mean: 8 waves x 32 keys (2 tiles), 256-key blocks, grid 256 ----------
__global__ __launch_bounds__(512) void k_amean(const unsigned short* __restrict__ Q,
                                               const unsigned short* __restrict__ Kc,
                                               const float* __restrict__ lrs,
                                               float* __restrict__ amean) {
    __shared__ __attribute__((aligned(16))) unsigned short Qlds[16384];  // 2 x 16KB
    __shared__ float rslds[2][128];
    int t = threadIdx.x, lane = t & 63, w = t >> 6;
    int quad = lane >> 4, c = lane & 15;
    int bi = blockIdx.x;
    int hb = bi & 31, kt = bi >> 5, b = hb & 1;
    const unsigned short* kbase = Kc + (size_t)hb * 131072 + (size_t)(kt * 256 + w * 32) * 64;
    const unsigned short* qbase = Q + (size_t)hb * 131072;

    // K A-frags in registers: 2 key-subtiles x 2 k-halves (m=key=c, k=d)
    bf16x8 kf[2][2];
#pragma unroll
    for (int ksub = 0; ksub < 2; ++ksub)
#pragma unroll
        for (int ks = 0; ks < 2; ++ks)
            kf[ksub][ks] = *(const bf16x8*)&kbase[(ksub * 16 + c) * 64 + ks * 32 + quad * 8];

    // prologue: stage chunk 0
#pragma unroll
    for (int i = 0; i < 2; ++i) {
        int ch = i * 512 + t;
        int row = ch >> 3, Bs = ch & 7;
        glds16(&qbase[row * 64 + ((Bs ^ (row & 7)) * 8)], (char*)Qlds + ch * 16);
    }
    if (t < 128) rslds[0][t] = lrs[hb * 2048 + t];

    f32x4 colacc[2];
    colacc[0] = (f32x4){0.f, 0.f, 0.f, 0.f};
    colacc[1] = (f32x4){0.f, 0.f, 0.f, 0.f};

    for (int qc = 0; qc < 16; ++qc) {
        const unsigned short* Qb = Qlds + (qc & 1) * 8192;
        __syncthreads();
        if (qc < 15) {
            unsigned short* Qn = Qlds + ((qc + 1) & 1) * 8192;
#pragma unroll
            for (int i = 0; i < 2; ++i) {
                int ch = i * 512 + t;
                int row = ch >> 3, Bs = ch & 7;
                glds16(&qbase[(size_t)(qc + 1) * 8192 + row * 64 + ((Bs ^ (row & 7)) * 8)],
                       (char*)Qn + ch * 16);
            }
            if (t < 128) rslds[(qc + 1) & 1][t] = lrs[hb * 2048 + (qc + 1) * 128 + t];
        }
#pragma unroll
        for (int qs = 0; qs < 8; ++qs) {
            f32x4 st[2];
            st[0] = (f32x4){0.f, 0.f, 0.f, 0.f};
            st[1] = (f32x4){0.f, 0.f, 0.f, 0.f};
#pragma unroll
            for (int ks = 0; ks < 2; ++ks) {
                bf16x8 qfr = *(const bf16x8*)&Qb[(qs * 16 + c) * 64 +
                                                 (((ks * 4 + quad) ^ (c & 7)) * 8)];
#pragma unroll
                for (int ksub = 0; ksub < 2; ++ksub)
                    st[ksub] = __builtin_amdgcn_mfma_f32_16x16x32_bf16(kf[ksub][ks], qfr,
                                                                       st[ksub], 0, 0, 0);
            }
            float rv = rslds[qc & 1][qs * 16 + c];
#pragma unroll
            for (int ksub = 0; ksub < 2; ++ksub)
#pragma unroll
                for (int r = 0; r < 4; ++r)
                    colacc[ksub][r] += __builtin_amdgcn_exp2f(st[ksub][r] + rv);
        }
    }
    // reduce over q-lanes (c bits), then one atomic per key
#pragma unroll
    for (int ksub = 0; ksub < 2; ++ksub)
#pragma unroll
        for (int r = 0; r < 4; ++r) {
            float v = colacc[ksub][r];
            v += __shfl_xor(v, 1);
            v += __shfl_xor(v, 2);
            v += __shfl_xor(v, 4);
            v += __shfl_xor(v, 8);
            if (c == 0)
                atomicAdd(&amean[b * 2048 + kt * 256 + w * 32 + ksub * 16 + quad * 4 + r], v);
        }
}

extern "C" void kernel_launch(void* const* d_in, const int* in_sizes, int n_in,
                              void* d_out, int out_size, void* d_ws, size_t ws_size,
                              hipStream_t stream) {
    const float* x = (const float*)d_in[0];
    const float* w_qkv = (const float*)d_in[1];
    const float* b_qkv = (const float*)d_in[2];
    const float* w_out = (const float*)d_in[3];
    const float* b_out = (const float*)d_in[4];
    float* out = (float*)d_out;
    float* amean = out + 4194304;

    unsigned short* ws = (unsigned short*)d_ws;
    unsigned short* x_bf = ws;                   // 4 Mi elems
    unsigned short* wqkvT = x_bf + 4194304;      // 3 Mi
    unsigned short* woutT = wqkvT + 3145728;     // 1 Mi
    unsigned short* q_bf = woutT + 1048576;      // 4 Mi  [HB][N][64], pre-scaled by EXP2SC
    unsigned short* k_bf = q_bf + 4194304;       // 4 Mi  [HB][N][64]
    unsigned short* vT_bf = k_bf + 4194304;      // 4 Mi  [HB][64][N]
    unsigned short* ctx_bf = vT_bf + 4194304;    // 4 Mi
    float* lrs = (float*)(ctx_bf + 4194304);     // 64 Ki floats

    k_prep<<<5121, 256, 0, stream>>>(x, x_bf, w_qkv, wqkvT, w_out, woutT, amean);
    k_gemm_qkv<<<dim3(24, 32), 256, 0, stream>>>(x_bf, wqkvT, b_qkv, q_bf, 4096, 3072, 1024);
    k_attn<<<256, 512, 0, stream>>>(q_bf, k_bf, vT_bf, ctx_bf, lrs);
    k_amean<<<256, 512, 0, stream>>>(q_bf, k_bf, lrs, amean);
    k_gemm_out<<<dim3(8, 64), 256, 0, stream>>>(ctx_bf, woutT, b_out, out, 4096, 1024, 1024);
}